// Round 15
// baseline (861.693 us; speedup 1.0000x reference)
//
#include <hip/hip_runtime.h>

typedef unsigned short u16;
typedef __attribute__((ext_vector_type(8))) short bf16x8;
typedef __attribute__((ext_vector_type(4))) float f32x4;

#define NB 64      // batch
#define NT 50      // time
#define NIN 256    // input dim
#define NH 2000    // hidden
#define HP 2048    // padded hidden
#define EPS 1e-4f

__device__ __forceinline__ u16 f2bf(float f) {
  unsigned x = __float_as_uint(f);
  x += 0x7fffu + ((x >> 16) & 1u);
  return (u16)(x >> 16);
}
__device__ __forceinline__ float bf2f(u16 u) {
  return __uint_as_float(((unsigned)u) << 16);
}

#define GLDS16(g, l) __builtin_amdgcn_global_load_lds( \
  (const __attribute__((address_space(1))) unsigned int*)(g), \
  (__attribute__((address_space(3))) unsigned int*)(l), 16, 0, 0)

// ---------------- fused convert kernel (1 dispatch) ----------------
__global__ __launch_bounds__(256)
void cvt_all_kernel(const float* __restrict__ x, const float* __restrict__ W0,
                    const float* __restrict__ Ws, u16* __restrict__ x16,
                    u16* __restrict__ W016, u16* __restrict__ Ws16) {
  int bid = blockIdx.x;
  union { u16 u[8]; uint4 v; } o;
  if (bid < 400) {
    int tid = bid * 256 + threadIdx.x;         // 102400
    int row = tid >> 5;                         // t*64+b
    int c8  = (tid & 31) << 3;
    int t = row >> 6, b = row & 63;
    const float* src = x + (size_t)(b * NT + t) * NIN + c8;
    float4 a = *(const float4*)src;
    float4 c = *(const float4*)(src + 4);
    o.u[0]=f2bf(a.x); o.u[1]=f2bf(a.y); o.u[2]=f2bf(a.z); o.u[3]=f2bf(a.w);
    o.u[4]=f2bf(c.x); o.u[5]=f2bf(c.y); o.u[6]=f2bf(c.z); o.u[7]=f2bf(c.w);
    *(uint4*)(x16 + (size_t)row * NIN + c8) = o.v;
  } else if (bid < 656) {
    int tid = (bid - 400) * 256 + threadIdx.x;  // 65536
    int r = tid >> 5;
    int c8 = (tid & 31) << 3;
    if (r < NH) {
      const float* src = W0 + (size_t)r * NIN + c8;
      float4 a = *(const float4*)src;
      float4 b = *(const float4*)(src + 4);
      o.u[0]=f2bf(a.x); o.u[1]=f2bf(a.y); o.u[2]=f2bf(a.z); o.u[3]=f2bf(a.w);
      o.u[4]=f2bf(b.x); o.u[5]=f2bf(b.y); o.u[6]=f2bf(b.z); o.u[7]=f2bf(b.w);
    } else {
      o.v = make_uint4(0,0,0,0);
    }
    *(uint4*)(W016 + (size_t)tid * 8) = o.v;
  } else {
    int tid = (bid - 656) * 256 + threadIdx.x;  // 10*2048*256
    int l  = tid >> 19;
    int r  = (tid >> 8) & 2047;
    int c8 = (tid & 255) << 3;
    if (r < NH && c8 < NH) {
      const float* src = Ws + (size_t)l * (NH * NH) + (size_t)r * NH + c8;
      float4 a = *(const float4*)src;
      float4 b = *(const float4*)(src + 4);
      o.u[0]=f2bf(a.x); o.u[1]=f2bf(a.y); o.u[2]=f2bf(a.z); o.u[3]=f2bf(a.w);
      o.u[4]=f2bf(b.x); o.u[5]=f2bf(b.y); o.u[6]=f2bf(b.z); o.u[7]=f2bf(b.w);
    } else {
      o.v = make_uint4(0,0,0,0);
    }
    *(uint4*)(Ws16 + (size_t)tid * 8) = o.v;
  }
}

// ---------------- GEMM + fused BatchNorm (B-operand via L2->VGPR, A via LDS) ----------------
// C(3200,2048) = A(3200,K bf16, t-major rows) @ W(2048,K bf16)^T
// R12 structure (tile 128x128, BK=64 -> 32 iters, 8 waves 2Mx4N of 64x32,
// grid 400, 2 blocks/CU, one vmcnt(0)+barrier per iter) with the B operand
// moved OUT of LDS: R14 measured 58.6 TB/s aggregate LDS traffic = 85% of the
// 69 TB/s ceiling -> LDS-BW-bound. B-fragments are plain row-major bf16x8 at
// (bn*128+wn*32+j*16+lr)*K + t*64+kk*32+lkb*8 — loaded straight to VGPRs from
// the L2-resident (XCD-affine) B-panel, prefetched one K-iter ahead into a
// parity-named double register set (compile-time indices only, rule #20).
// LDS traffic/CU-iter: 256 -> 160 KB (-37%). L2 adds 1 MB/block (~1.8 TB/s
// per XCD, under the 4.3 ceiling) with a full-iter (~2000cy) landing window.
// A path unchanged: gload_lds + both-sides XOR-swizzle (rule #21).
// Ledger: iter t issues LOADB(t+1)+STAGEA(t+1) BEFORE computing tile t; the
// end-of-iter vmcnt(0) (cheap — loads had the whole iter to land) + barrier
// publishes A(t+1) and guarantees B(t+1) regs. WAR as in R12.
__global__ __launch_bounds__(512, 4)
void gemm_bn_kernel(const u16* __restrict__ A, const u16* __restrict__ W,
                    u16* __restrict__ Mn, const float* __restrict__ g,
                    const float* __restrict__ be, int K) {
  __shared__ u16 As[2 * 128 * 64];   // 32 KiB (A only)
  const int tid = threadIdx.x;
  const int w = tid >> 6, l = tid & 63;
  const int wm = w >> 2, wn = w & 3;          // 2M x 4N waves, wave = 64x32
  const int bid = blockIdx.x;
  const int xcd = bid & 7;
  const int r0  = bid >> 3;                   // 0..49
  const int hi  = r0 >= 25;
  const int bn  = xcd + (hi << 3);            // 0..15, same-XCD panel pair
  const int bm  = r0 - 25 * hi;               // 0..24
  f32x4 acc[4][2] = {};
  const u16* Ab = A + (size_t)bm * 128 * K;
  const u16* Wb = W + (size_t)bn * 128 * K;

  // A staging (unchanged from R12): wave w stages A-rows [16w,16w+16).
  const int rib  = l >> 3;                    // 0..7
  const int scbs = (l & 7) ^ rib;             // pre-swizzled source col-block
  const size_t goff1 = (size_t)((2 * w    ) * 8 + rib) * K + scbs * 8;
  const size_t goff2 = (size_t)((2 * w + 1) * 8 + rib) * K + scbs * 8;
  const int lr  = l & 15;
  const int lkb = l >> 4;                     // 0..3 k-subblock
  const int nk  = K >> 6;

  // B-fragment base for this lane: row = bn*128 + wn*32 + lr, k-offset lkb*8
  const u16* Bf = Wb + (size_t)(wn * 32 + lr) * K + lkb * 8;

#define STAGEA(tt, bi) do {                                             \
    GLDS16(Ab + goff1 + (tt) * 64, As + (bi) * 8192 + (2*w    ) * 512); \
    GLDS16(Ab + goff2 + (tt) * 64, As + (bi) * 8192 + (2*w + 1) * 512); \
  } while (0)

#define LOADB(bset, tt) do {                                            \
    bset[0][0] = *(const bf16x8*)(Bf           + (tt) * 64);            \
    bset[0][1] = *(const bf16x8*)(Bf           + (tt) * 64 + 32);       \
    bset[1][0] = *(const bf16x8*)(Bf + 16 * K  + (tt) * 64);            \
    bset[1][1] = *(const bf16x8*)(Bf + 16 * K  + (tt) * 64 + 32);       \
  } while (0)

#define COMPUTE(bi, bset) do {                                          \
    const u16* Ac = As + (bi) * 8192;                                   \
    _Pragma("unroll")                                                   \
    for (int kk = 0; kk < 2; ++kk) {                                    \
      bf16x8 af[4];                                                     \
      const int cb = ((kk * 4 + lkb) ^ (lr & 7)) * 8;                   \
      _Pragma("unroll")                                                 \
      for (int i = 0; i < 4; ++i)                                       \
        af[i] = *(const bf16x8*)(Ac + (wm * 64 + i * 16 + lr) * 64 + cb); \
      __builtin_amdgcn_s_setprio(1);                                    \
      _Pragma("unroll")                                                 \
      for (int i = 0; i < 4; ++i)                                       \
        _Pragma("unroll")                                               \
        for (int j = 0; j < 2; ++j)                                     \
          acc[i][j] = __builtin_amdgcn_mfma_f32_16x16x32_bf16(          \
              af[i], bset[j][kk], acc[i][j], 0, 0, 0);                  \
      __builtin_amdgcn_s_setprio(0);                                    \
    }                                                                   \
  } while (0)

  bf16x8 b0[2][2], b1[2][2];

  // prologue: tile 0 (B-regs + A-LDS) in flight, drained, published
  LOADB(b0, 0);
  STAGEA(0, 0);
  asm volatile("s_waitcnt vmcnt(0)" ::: "memory");
  __builtin_amdgcn_s_barrier();

  // nk is even (K=2048 -> 32, K=256 -> 4): process pairs, parity-named sets
  for (int t = 0; t < nk; t += 2) {
    // even iter: compute (buf0, b0), prefetch t+1 -> (buf1, b1)
    if (t + 1 < nk) { LOADB(b1, t + 1); STAGEA(t + 1, 1); }
    COMPUTE(0, b0);
    asm volatile("s_waitcnt vmcnt(0)" ::: "memory");
    __builtin_amdgcn_s_barrier();
    // odd iter: compute (buf1, b1), prefetch t+2 -> (buf0, b0)
    if (t + 2 < nk) { LOADB(b0, t + 2); STAGEA(t + 2, 0); }
    COMPUTE(1, b1);
    asm volatile("s_waitcnt vmcnt(0)" ::: "memory");
    __builtin_amdgcn_s_barrier();
  }
#undef STAGEA
#undef LOADB
#undef COMPUTE

  // ---- fused BN epilogue: stats over the wave's 64 rows (= full batch of one t)
  const int lg = l >> 4;
  const int rbase = bm * 128 + wm * 64;
  const int cbase = bn * 128 + wn * 32;
#pragma unroll
  for (int j = 0; j < 2; ++j) {
    float s = 0.f, s2 = 0.f;
#pragma unroll
    for (int i = 0; i < 4; ++i)
#pragma unroll
      for (int r = 0; r < 4; ++r) { float v = acc[i][j][r]; s += v; s2 += v * v; }
    s  += __shfl_xor(s, 16);  s2 += __shfl_xor(s2, 16);
    s  += __shfl_xor(s, 32);  s2 += __shfl_xor(s2, 32);
    float mu  = s * (1.f / 64.f);
    float var = fmaxf(s2 * (1.f / 64.f) - mu * mu, 0.f);
    int col = cbase + j * 16 + lr;
    bool ok = col < NH;
    float gg = ok ? g[col]  : 0.f;
    float bb = ok ? be[col] : 0.f;
    float sc = rsqrtf(var + EPS) * gg;
#pragma unroll
    for (int i = 0; i < 4; ++i) {
      int row0 = rbase + i * 16 + lg * 4;
#pragma unroll
      for (int r = 0; r < 4; ++r)
        Mn[(size_t)(row0 + r) * HP + col] = f2bf((acc[i][j][r] - mu) * sc + bb);
    }
  }
}

// ---------------- IndRNN scans: all-prefetch, branch-free ----------------
__device__ __forceinline__ void pad16(u16* out16, int b, int h) {
#pragma unroll
  for (int t = 0; t < NT; ++t)
    *(unsigned*)(out16 + (size_t)(t * NB + b) * HP + h) = 0u;
}

// first-of-pair: Mn -> bf16 activation only
__global__ void scan_a_kernel(const u16* __restrict__ Mn, const float* __restrict__ u,
                              u16* __restrict__ out16) {
  int tid = blockIdx.x * 256 + threadIdx.x;   // 65536
  int h2 = tid & 1023, b = tid >> 10;
  int h = h2 << 1;
  if (h >= NH) { pad16(out16, b, h); return; }
  unsigned mv[NT];
#pragma unroll
  for (int t = 0; t < NT; ++t)
    mv[t] = *(const unsigned*)(Mn + (size_t)(t * NB + b) * HP + h);
  float2 uu = *(const float2*)(u + h);
  float h0 = 0.f, h1 = 0.f;
#pragma unroll
  for (int t = 0; t < NT; ++t) {
    h0 = fmaxf(fmaf(uu.x, h0, bf2f((u16)(mv[t] & 0xffffu))), 0.f);
    h1 = fmaxf(fmaf(uu.y, h1, bf2f((u16)(mv[t] >> 16))), 0.f);
    *(unsigned*)(out16 + (size_t)(t * NB + b) * HP + h) =
        (unsigned)f2bf(h0) | ((unsigned)f2bf(h1) << 16);
  }
}

// second-of-pair / stem: out16 = bf16(scan [+ res16]) — activation AND residual
template<bool HASRES>
__global__ void scan_b_kernel(const u16* __restrict__ Mn, const float* __restrict__ u,
                              const u16* __restrict__ res16, u16* __restrict__ out16) {
  int tid = blockIdx.x * 256 + threadIdx.x;   // 65536
  int h2 = tid & 1023, b = tid >> 10;
  int h = h2 << 1;
  if (h >= NH) { pad16(out16, b, h); return; }
  unsigned mv[NT];
#pragma unroll
  for (int t = 0; t < NT; ++t)
    mv[t] = *(const unsigned*)(Mn + (size_t)(t * NB + b) * HP + h);
  unsigned rv[NT];
  if (HASRES) {
#pragma unroll
    for (int t = 0; t < NT; ++t)
      rv[t] = *(const unsigned*)(res16 + (size_t)(t * NB + b) * HP + h);
  }
  float2 uu = *(const float2*)(u + h);
  float h0 = 0.f, h1 = 0.f;
#pragma unroll
  for (int t = 0; t < NT; ++t) {
    h0 = fmaxf(fmaf(uu.x, h0, bf2f((u16)(mv[t] & 0xffffu))), 0.f);
    h1 = fmaxf(fmaf(uu.y, h1, bf2f((u16)(mv[t] >> 16))), 0.f);
    float o0 = h0, o1 = h1;
    if (HASRES) {
      o0 += bf2f((u16)(rv[t] & 0xffffu));
      o1 += bf2f((u16)(rv[t] >> 16));
    }
    *(unsigned*)(out16 + (size_t)(t * NB + b) * HP + h) =
        (unsigned)f2bf(o0) | ((unsigned)f2bf(o1) << 16);
  }
}

// last layer: out = scan + res16, written b-major f32 (stride NH)
__global__ void scan_c_kernel(const u16* __restrict__ Mn, const float* __restrict__ u,
                              const u16* __restrict__ res16, float* __restrict__ out) {
  int tid = blockIdx.x * 256 + threadIdx.x;   // 65536
  int h2 = tid & 1023, b = tid >> 10;
  int h = h2 << 1;
  if (h >= NH) return;
  unsigned mv[NT];
#pragma unroll
  for (int t = 0; t < NT; ++t)
    mv[t] = *(const unsigned*)(Mn + (size_t)(t * NB + b) * HP + h);
  unsigned rv[NT];
#pragma unroll
  for (int t = 0; t < NT; ++t)
    rv[t] = *(const unsigned*)(res16 + (size_t)(t * NB + b) * HP + h);
  float2 uu = *(const float2*)(u + h);
  float h0 = 0.f, h1 = 0.f;
#pragma unroll
  for (int t = 0; t < NT; ++t) {
    h0 = fmaxf(fmaf(uu.x, h0, bf2f((u16)(mv[t] & 0xffffu))), 0.f);
    h1 = fmaxf(fmaf(uu.y, h1, bf2f((u16)(mv[t] >> 16))), 0.f);
    *(float2*)(out + (size_t)(b * NT + t) * NH + h) =
        make_float2(h0 + bf2f((u16)(rv[t] & 0xffffu)),
                    h1 + bf2f((u16)(rv[t] >> 16)));
  }
}

// ---------------- orchestration ----------------
extern "C" void kernel_launch(void* const* d_in, const int* in_sizes, int n_in,
                              void* d_out, int out_size, void* d_ws, size_t ws_size,
                              hipStream_t stream) {
  const float* x   = (const float*)d_in[0];
  const float* W0  = (const float*)d_in[1];
  // d_in[2] = b0 (cancels in BN)
  const float* u0  = (const float*)d_in[3];
  const float* g0  = (const float*)d_in[4];
  const float* be0 = (const float*)d_in[5];
  const float* Ws  = (const float*)d_in[6];
  // d_in[7] = bs (cancels in BN)
  const float* us  = (const float*)d_in[8];
  const float* gs  = (const float*)d_in[9];
  const float* bes = (const float*)d_in[10];
  float* out = (float*)d_out;

  char* ws = (char*)d_ws;
  u16*   x16  = (u16*)  (ws + 0);           // 3200*256*2      = 1,638,400
  u16*   W016 = (u16*)  (ws + 1638400);     // 2048*256*2      = 1,048,576
  u16*   Ws16 = (u16*)  (ws + 2686976);     // 10*2048*2048*2  = 83,886,080
  u16*   Mbuf = (u16*)  (ws + 86573056);    // 3200*2048*2     = 13,107,200
  u16*   A16  = (u16*)  (ws + 99680256);    // 3200*2048*2     = 13,107,200 (activation+residual)
  u16*   B16  = (u16*)  (ws + 112787456);   // 3200*2048*2     = 13,107,200

  // fused converts (x, W0, Ws in one dispatch)
  cvt_all_kernel<<<21136, 256, 0, stream>>>(x, W0, Ws, x16, W016, Ws16);

  // stem layer: x @ W0^T, K=256, fused BN; scan writes A16 (activation+residual)
  gemm_bn_kernel<<<400, 512, 0, stream>>>(x16, W016, Mbuf, g0, be0, NIN);
  scan_b_kernel<false><<<256, 256, 0, stream>>>(Mbuf, u0, nullptr, A16);

  for (int l = 0; l < 10; ++l) {
    const u16* Ain = (l & 1) ? B16 : A16;
    gemm_bn_kernel<<<400, 512, 0, stream>>>(Ain, Ws16 + (size_t)l * HP * HP, Mbuf,
                                            gs + (size_t)l * NH, bes + (size_t)l * NH, HP);
    const float* ul = us + (size_t)l * NH;
    if ((l & 1) == 0) {
      scan_a_kernel<<<256, 256, 0, stream>>>(Mbuf, ul, B16);
    } else if (l < 9) {
      // new A16 = bf16(scan + old A16): next activation AND next residual
      scan_b_kernel<true><<<256, 256, 0, stream>>>(Mbuf, ul, A16, A16);
    } else {
      scan_c_kernel<<<256, 256, 0, stream>>>(Mbuf, ul, A16, out);
    }
  }
}

// Round 16
// 503.475 us; speedup vs baseline: 1.7115x; 1.7115x over previous
//
#include <hip/hip_runtime.h>

typedef unsigned short u16;
typedef __attribute__((ext_vector_type(8))) short bf16x8;
typedef __attribute__((ext_vector_type(4))) float f32x4;

#define NB 64      // batch
#define NT 50      // time
#define NIN 256    // input dim
#define NH 2000    // hidden
#define HP 2048    // padded hidden
#define EPS 1e-4f

__device__ __forceinline__ u16 f2bf(float f) {
  unsigned x = __float_as_uint(f);
  x += 0x7fffu + ((x >> 16) & 1u);
  return (u16)(x >> 16);
}
__device__ __forceinline__ float bf2f(u16 u) {
  return __uint_as_float(((unsigned)u) << 16);
}

#define GLDS16(g, l) __builtin_amdgcn_global_load_lds( \
  (const __attribute__((address_space(1))) unsigned int*)(g), \
  (__attribute__((address_space(3))) unsigned int*)(l), 16, 0, 0)

// ---------------- fused convert kernel (1 dispatch) ----------------
__global__ __launch_bounds__(256)
void cvt_all_kernel(const float* __restrict__ x, const float* __restrict__ W0,
                    const float* __restrict__ Ws, u16* __restrict__ x16,
                    u16* __restrict__ W016, u16* __restrict__ Ws16) {
  int bid = blockIdx.x;
  union { u16 u[8]; uint4 v; } o;
  if (bid < 400) {
    int tid = bid * 256 + threadIdx.x;         // 102400
    int row = tid >> 5;                         // t*64+b
    int c8  = (tid & 31) << 3;
    int t = row >> 6, b = row & 63;
    const float* src = x + (size_t)(b * NT + t) * NIN + c8;
    float4 a = *(const float4*)src;
    float4 c = *(const float4*)(src + 4);
    o.u[0]=f2bf(a.x); o.u[1]=f2bf(a.y); o.u[2]=f2bf(a.z); o.u[3]=f2bf(a.w);
    o.u[4]=f2bf(c.x); o.u[5]=f2bf(c.y); o.u[6]=f2bf(c.z); o.u[7]=f2bf(c.w);
    *(uint4*)(x16 + (size_t)row * NIN + c8) = o.v;
  } else if (bid < 656) {
    int tid = (bid - 400) * 256 + threadIdx.x;  // 65536
    int r = tid >> 5;
    int c8 = (tid & 31) << 3;
    if (r < NH) {
      const float* src = W0 + (size_t)r * NIN + c8;
      float4 a = *(const float4*)src;
      float4 b = *(const float4*)(src + 4);
      o.u[0]=f2bf(a.x); o.u[1]=f2bf(a.y); o.u[2]=f2bf(a.z); o.u[3]=f2bf(a.w);
      o.u[4]=f2bf(b.x); o.u[5]=f2bf(b.y); o.u[6]=f2bf(b.z); o.u[7]=f2bf(b.w);
    } else {
      o.v = make_uint4(0,0,0,0);
    }
    *(uint4*)(W016 + (size_t)tid * 8) = o.v;
  } else {
    int tid = (bid - 656) * 256 + threadIdx.x;  // 10*2048*256
    int l  = tid >> 19;
    int r  = (tid >> 8) & 2047;
    int c8 = (tid & 255) << 3;
    if (r < NH && c8 < NH) {
      const float* src = Ws + (size_t)l * (NH * NH) + (size_t)r * NH + c8;
      float4 a = *(const float4*)src;
      float4 b = *(const float4*)(src + 4);
      o.u[0]=f2bf(a.x); o.u[1]=f2bf(a.y); o.u[2]=f2bf(a.z); o.u[3]=f2bf(a.w);
      o.u[4]=f2bf(b.x); o.u[5]=f2bf(b.y); o.u[6]=f2bf(b.z); o.u[7]=f2bf(b.w);
    } else {
      o.v = make_uint4(0,0,0,0);
    }
    *(uint4*)(Ws16 + (size_t)tid * 8) = o.v;
  }
}

// ---------------- GEMM + fused BatchNorm (R12 config: best measured, 750 TF) ----------------
// C(3200,2048) = A(3200,K bf16, t-major rows) @ W(2048,K bf16)^T
// Tile 128x128, BK=64 -> 32 K-iters. 8 waves as 2M x 4N -> per-wave 64x32;
// wave-row wm = one timestep -> BN stats wave-local. Grid 400, 2 blocks/CU
// (LDS 64 KiB), 16 waves/CU = 4/SIMD: the TLP that hides the per-iter
// barrier rendezvous (R13: 4-wave variant lost 14 µs; R15: B-via-registers
// lost 350 µs to uncoalesced loads — both confirm this config).
// Double-buffered: iter t issues STAGE(t+1 -> buf p^1) BEFORE computing
// buf p (full-iteration landing window covers L3 ~900 cy); one
// vmcnt(0)+barrier per iter. WAR: buf p's ds_reads are consumed by same-iter
// MFMAs (compiler lgkm) before the end-of-iter barrier; p is overwritten
// only two barriers later.
// LDS XOR-swizzle both-sides (rule #21): source col-block pre-swizzled
// scbs=(l&7)^(l>>3) (gload_lds dest linear), ds_read cb=(kk*4+lkb)^(lr&7).
// XCD-affine: XCD x owns B-panels {x, x+8} (L2-resident).
__global__ __launch_bounds__(512, 4)
void gemm_bn_kernel(const u16* __restrict__ A, const u16* __restrict__ W,
                    u16* __restrict__ Mn, const float* __restrict__ g,
                    const float* __restrict__ be, int K) {
  __shared__ u16 As[2 * 128 * 64];   // 32 KiB
  __shared__ u16 Bs[2 * 128 * 64];   // 32 KiB
  const int tid = threadIdx.x;
  const int w = tid >> 6, l = tid & 63;
  const int wm = w >> 2, wn = w & 3;          // 2M x 4N waves, wave = 64x32
  const int bid = blockIdx.x;
  const int xcd = bid & 7;
  const int r0  = bid >> 3;                   // 0..49
  const int hi  = r0 >= 25;
  const int bn  = xcd + (hi << 3);            // 0..15, same-XCD panel pair
  const int bm  = r0 - 25 * hi;               // 0..24
  f32x4 acc[4][2] = {};
  const u16* Ab = A + (size_t)bm * 128 * K;
  const u16* Wb = W + (size_t)bn * 128 * K;

  // staging: 1 load = 8 rows x 128B (64 cols bf16). Wave w stages A-rows and
  // B-rows [16w, 16w+16) = 2 loads each. Lane l: row-in-block l>>3, source
  // 16B col-block pre-swizzled:
  const int rib  = l >> 3;                    // 0..7
  const int scbs = (l & 7) ^ rib;             // pre-swizzled source col-block
  const size_t goff1 = (size_t)((2 * w    ) * 8 + rib) * K + scbs * 8;
  const size_t goff2 = (size_t)((2 * w + 1) * 8 + rib) * K + scbs * 8;
  const int lr  = l & 15;
  const int lkb = l >> 4;                     // 0..3 k-subblock
  const int nk  = K >> 6;

#define STAGE(tt, bi) do {                                              \
    GLDS16(Ab + goff1 + (tt) * 64, As + (bi) * 8192 + (2*w    ) * 512); \
    GLDS16(Ab + goff2 + (tt) * 64, As + (bi) * 8192 + (2*w + 1) * 512); \
    GLDS16(Wb + goff1 + (tt) * 64, Bs + (bi) * 8192 + (2*w    ) * 512); \
    GLDS16(Wb + goff2 + (tt) * 64, Bs + (bi) * 8192 + (2*w + 1) * 512); \
  } while (0)

  // prologue: tile 0 staged, drained, published
  STAGE(0, 0);
  asm volatile("s_waitcnt vmcnt(0)" ::: "memory");
  __builtin_amdgcn_s_barrier();

  int p = 0;
  for (int t = 0; t < nk; ++t) {
    if (t + 1 < nk) STAGE(t + 1, p ^ 1);   // lands during this iter's compute
    const u16* Ac = As + p * 8192;
    const u16* Bc = Bs + p * 8192;
#pragma unroll
    for (int kk = 0; kk < 2; ++kk) {
      bf16x8 af[4], bfr[2];
      const int cb = ((kk * 4 + lkb) ^ (lr & 7)) * 8;
#pragma unroll
      for (int i = 0; i < 4; ++i)
        af[i] = *(const bf16x8*)(Ac + (wm * 64 + i * 16 + lr) * 64 + cb);
#pragma unroll
      for (int j = 0; j < 2; ++j)
        bfr[j] = *(const bf16x8*)(Bc + (wn * 32 + j * 16 + lr) * 64 + cb);
      __builtin_amdgcn_s_setprio(1);
#pragma unroll
      for (int i = 0; i < 4; ++i)
#pragma unroll
        for (int j = 0; j < 2; ++j)
          acc[i][j] = __builtin_amdgcn_mfma_f32_16x16x32_bf16(af[i], bfr[j], acc[i][j], 0, 0, 0);
      __builtin_amdgcn_s_setprio(0);
    }
    asm volatile("s_waitcnt vmcnt(0)" ::: "memory");  // t+1's loads landed
    __builtin_amdgcn_s_barrier();                     // publish buf p^1
    p ^= 1;
  }
#undef STAGE

  // ---- fused BN epilogue: stats over the wave's 64 rows (= full batch of one t)
  const int lg = l >> 4;
  const int rbase = bm * 128 + wm * 64;
  const int cbase = bn * 128 + wn * 32;
#pragma unroll
  for (int j = 0; j < 2; ++j) {
    float s = 0.f, s2 = 0.f;
#pragma unroll
    for (int i = 0; i < 4; ++i)
#pragma unroll
      for (int r = 0; r < 4; ++r) { float v = acc[i][j][r]; s += v; s2 += v * v; }
    s  += __shfl_xor(s, 16);  s2 += __shfl_xor(s2, 16);
    s  += __shfl_xor(s, 32);  s2 += __shfl_xor(s2, 32);
    float mu  = s * (1.f / 64.f);
    float var = fmaxf(s2 * (1.f / 64.f) - mu * mu, 0.f);
    int col = cbase + j * 16 + lr;
    bool ok = col < NH;
    float gg = ok ? g[col]  : 0.f;
    float bb = ok ? be[col] : 0.f;
    float sc = rsqrtf(var + EPS) * gg;
#pragma unroll
    for (int i = 0; i < 4; ++i) {
      int row0 = rbase + i * 16 + lg * 4;
#pragma unroll
      for (int r = 0; r < 4; ++r)
        Mn[(size_t)(row0 + r) * HP + col] = f2bf((acc[i][j][r] - mu) * sc + bb);
    }
  }
}

// ---------------- IndRNN scans: all-prefetch, branch-free ----------------
__device__ __forceinline__ void pad16(u16* out16, int b, int h) {
#pragma unroll
  for (int t = 0; t < NT; ++t)
    *(unsigned*)(out16 + (size_t)(t * NB + b) * HP + h) = 0u;
}

// first-of-pair: Mn -> bf16 activation only
__global__ void scan_a_kernel(const u16* __restrict__ Mn, const float* __restrict__ u,
                              u16* __restrict__ out16) {
  int tid = blockIdx.x * 256 + threadIdx.x;   // 65536
  int h2 = tid & 1023, b = tid >> 10;
  int h = h2 << 1;
  if (h >= NH) { pad16(out16, b, h); return; }
  unsigned mv[NT];
#pragma unroll
  for (int t = 0; t < NT; ++t)
    mv[t] = *(const unsigned*)(Mn + (size_t)(t * NB + b) * HP + h);
  float2 uu = *(const float2*)(u + h);
  float h0 = 0.f, h1 = 0.f;
#pragma unroll
  for (int t = 0; t < NT; ++t) {
    h0 = fmaxf(fmaf(uu.x, h0, bf2f((u16)(mv[t] & 0xffffu))), 0.f);
    h1 = fmaxf(fmaf(uu.y, h1, bf2f((u16)(mv[t] >> 16))), 0.f);
    *(unsigned*)(out16 + (size_t)(t * NB + b) * HP + h) =
        (unsigned)f2bf(h0) | ((unsigned)f2bf(h1) << 16);
  }
}

// second-of-pair / stem: out16 = bf16(scan [+ res16]) — activation AND residual
template<bool HASRES>
__global__ void scan_b_kernel(const u16* __restrict__ Mn, const float* __restrict__ u,
                              const u16* __restrict__ res16, u16* __restrict__ out16) {
  int tid = blockIdx.x * 256 + threadIdx.x;   // 65536
  int h2 = tid & 1023, b = tid >> 10;
  int h = h2 << 1;
  if (h >= NH) { pad16(out16, b, h); return; }
  unsigned mv[NT];
#pragma unroll
  for (int t = 0; t < NT; ++t)
    mv[t] = *(const unsigned*)(Mn + (size_t)(t * NB + b) * HP + h);
  unsigned rv[NT];
  if (HASRES) {
#pragma unroll
    for (int t = 0; t < NT; ++t)
      rv[t] = *(const unsigned*)(res16 + (size_t)(t * NB + b) * HP + h);
  }
  float2 uu = *(const float2*)(u + h);
  float h0 = 0.f, h1 = 0.f;
#pragma unroll
  for (int t = 0; t < NT; ++t) {
    h0 = fmaxf(fmaf(uu.x, h0, bf2f((u16)(mv[t] & 0xffffu))), 0.f);
    h1 = fmaxf(fmaf(uu.y, h1, bf2f((u16)(mv[t] >> 16))), 0.f);
    float o0 = h0, o1 = h1;
    if (HASRES) {
      o0 += bf2f((u16)(rv[t] & 0xffffu));
      o1 += bf2f((u16)(rv[t] >> 16));
    }
    *(unsigned*)(out16 + (size_t)(t * NB + b) * HP + h) =
        (unsigned)f2bf(o0) | ((unsigned)f2bf(o1) << 16);
  }
}

// last layer: out = scan + res16, written b-major f32 (stride NH)
__global__ void scan_c_kernel(const u16* __restrict__ Mn, const float* __restrict__ u,
                              const u16* __restrict__ res16, float* __restrict__ out) {
  int tid = blockIdx.x * 256 + threadIdx.x;   // 65536
  int h2 = tid & 1023, b = tid >> 10;
  int h = h2 << 1;
  if (h >= NH) return;
  unsigned mv[NT];
#pragma unroll
  for (int t = 0; t < NT; ++t)
    mv[t] = *(const unsigned*)(Mn + (size_t)(t * NB + b) * HP + h);
  unsigned rv[NT];
#pragma unroll
  for (int t = 0; t < NT; ++t)
    rv[t] = *(const unsigned*)(res16 + (size_t)(t * NB + b) * HP + h);
  float2 uu = *(const float2*)(u + h);
  float h0 = 0.f, h1 = 0.f;
#pragma unroll
  for (int t = 0; t < NT; ++t) {
    h0 = fmaxf(fmaf(uu.x, h0, bf2f((u16)(mv[t] & 0xffffu))), 0.f);
    h1 = fmaxf(fmaf(uu.y, h1, bf2f((u16)(mv[t] >> 16))), 0.f);
    *(float2*)(out + (size_t)(b * NT + t) * NH + h) =
        make_float2(h0 + bf2f((u16)(rv[t] & 0xffffu)),
                    h1 + bf2f((u16)(rv[t] >> 16)));
  }
}

// ---------------- orchestration ----------------
extern "C" void kernel_launch(void* const* d_in, const int* in_sizes, int n_in,
                              void* d_out, int out_size, void* d_ws, size_t ws_size,
                              hipStream_t stream) {
  const float* x   = (const float*)d_in[0];
  const float* W0  = (const float*)d_in[1];
  // d_in[2] = b0 (cancels in BN)
  const float* u0  = (const float*)d_in[3];
  const float* g0  = (const float*)d_in[4];
  const float* be0 = (const float*)d_in[5];
  const float* Ws  = (const float*)d_in[6];
  // d_in[7] = bs (cancels in BN)
  const float* us  = (const float*)d_in[8];
  const float* gs  = (const float*)d_in[9];
  const float* bes = (const float*)d_in[10];
  float* out = (float*)d_out;

  char* ws = (char*)d_ws;
  u16*   x16  = (u16*)  (ws + 0);           // 3200*256*2      = 1,638,400
  u16*   W016 = (u16*)  (ws + 1638400);     // 2048*256*2      = 1,048,576
  u16*   Ws16 = (u16*)  (ws + 2686976);     // 10*2048*2048*2  = 83,886,080
  u16*   Mbuf = (u16*)  (ws + 86573056);    // 3200*2048*2     = 13,107,200
  u16*   A16  = (u16*)  (ws + 99680256);    // 3200*2048*2     = 13,107,200 (activation+residual)
  u16*   B16  = (u16*)  (ws + 112787456);   // 3200*2048*2     = 13,107,200

  // fused converts (x, W0, Ws in one dispatch)
  cvt_all_kernel<<<21136, 256, 0, stream>>>(x, W0, Ws, x16, W016, Ws16);

  // stem layer: x @ W0^T, K=256, fused BN; scan writes A16 (activation+residual)
  gemm_bn_kernel<<<400, 512, 0, stream>>>(x16, W016, Mbuf, g0, be0, NIN);
  scan_b_kernel<false><<<256, 256, 0, stream>>>(Mbuf, u0, nullptr, A16);

  for (int l = 0; l < 10; ++l) {
    const u16* Ain = (l & 1) ? B16 : A16;
    gemm_bn_kernel<<<400, 512, 0, stream>>>(Ain, Ws16 + (size_t)l * HP * HP, Mbuf,
                                            gs + (size_t)l * NH, bes + (size_t)l * NH, HP);
    const float* ul = us + (size_t)l * NH;
    if ((l & 1) == 0) {
      scan_a_kernel<<<256, 256, 0, stream>>>(Mbuf, ul, B16);
    } else if (l < 9) {
      // new A16 = bf16(scan + old A16): next activation AND next residual
      scan_b_kernel<true><<<256, 256, 0, stream>>>(Mbuf, ul, A16, A16);
    } else {
      scan_c_kernel<<<256, 256, 0, stream>>>(Mbuf, ul, A16, out);
    }
  }
}